// Round 8
// baseline (474.143 us; speedup 1.0000x reference)
//
#include <hip/hip_runtime.h>
#include <hip/hip_bf16.h>

// BitLevelMapper: bits [B,16] int32 {0,1} (mem index j holds value bit 15-j),
// tables [16, 32768] float32 {0,1}. For bit i: addr = value of bits 0..i-1,
// flip = tables[i][addr], out bit i = bit i ^ flip. Output float32, reversed
// layout like input.
//
// R6 (best, 428.9 us e2e; fixed harness overhead C~283 us -> ours ~146 us):
// split into unidirectional passes via 8 MB intermediate.
// R8: ATTRIBUTION PROBE — identical to R6 but expand_kernel launched TWICE
// (idempotent). e2e_R8 - e2e_R6 = expand's exact duration, which top-5
// rocprof hides (everything of ours is under the 163 us fill cutoff).

#define PACK_WORDS 2048   // 65536 bits (65535 used), 8 KB

typedef float vfloat4 __attribute__((ext_vector_type(4)));

__global__ __launch_bounds__(256) void
pack_tables_kernel(const float* __restrict__ tables, unsigned* __restrict__ packed) {
    int g = blockIdx.x * blockDim.x + threadIdx.x;   // global bit index
    bool val = false;
    if (g < 65535) {
        int i = 31 - __clz(g + 1);            // row: (2^i - 1) <= g < (2^{i+1} - 1)
        int a = g - ((1 << i) - 1);           // address within row
        val = tables[i * 32768 + a] != 0.0f;
    }
    unsigned long long m = __ballot(val);
    if ((threadIdx.x & 63) == 0) {            // one writer per wave, 2 words
        packed[(g >> 5)]     = (unsigned)m;
        packed[(g >> 5) + 1] = (unsigned)(m >> 32);
    }
}

// Pass A: bits (int32 {0,1}) -> packed 16-bit row values (8 MB).
// Lane t loads quarter q=t&3 of row r=t>>2 (16 B, fully coalesced);
// quad OR-butterfly assembles v; one ushort store per quad.
__global__ __launch_bounds__(256) void
compress_kernel(const int4* __restrict__ bits4, unsigned short* __restrict__ rowv) {
    int t = blockIdx.x * 256 + threadIdx.x;
    int4 m = bits4[t];
    // nib bit3 = first element in memory order = value bit 15-4q
    unsigned nb = (unsigned)((m.x << 3) | (m.y << 2) | (m.z << 1) | m.w);
    unsigned part = nb << (12 - ((t & 3) << 2));
    part |= (unsigned)__shfl_xor((int)part, 1, 64);
    part |= (unsigned)__shfl_xor((int)part, 2, 64);
    if ((t & 3) == 0)
        rowv[t >> 2] = (unsigned short)part;  // rows consecutive per wave
}

// Pass B: packed row values + packed table -> float32 output (256 MB).
// Thread handles 4 quarter-rows (one float4 nt store each, coalesced).
__global__ __launch_bounds__(256) void
expand_kernel(const unsigned short* __restrict__ rowv,
              const unsigned* __restrict__ packed,
              vfloat4* __restrict__ out4) {
    __shared__ unsigned tab[PACK_WORDS];
    {   // stage 8 KB table (512 int4 / 256 threads = 2 each)
        const int4* p4 = (const int4*)packed;
        int4* t4 = (int4*)tab;
        t4[threadIdx.x]       = p4[threadIdx.x];
        t4[threadIdx.x + 256] = p4[threadIdx.x + 256];
    }
    __syncthreads();

    const size_t base = (size_t)blockIdx.x * 1024 + threadIdx.x;
    const int q4 = (int)(threadIdx.x & 3) << 2;      // 4*q, invariant across iters
    #pragma unroll
    for (int it = 0; it < 4; ++it) {
        size_t t = base + (size_t)it * 256;          // quarter index
        unsigned v = rowv[t >> 2];                   // 4 lanes share a row
        float o[4];
        #pragma unroll
        for (int j = 0; j < 4; ++j) {
            int i = 15 - q4 - j;                     // value bit for this slot
            unsigned mask = (1u << i) - 1u;
            unsigned bidx = mask + (v & mask);       // (2^i-1) + addr
            unsigned fl   = tab[bidx >> 5] >> (bidx & 31u);
            o[j] = (float)(((v >> i) ^ fl) & 1u);
        }
        vfloat4 f = {o[0], o[1], o[2], o[3]};
        __builtin_nontemporal_store(f, &out4[t]);
    }
}

extern "C" void kernel_launch(void* const* d_in, const int* in_sizes, int n_in,
                              void* d_out, int out_size, void* d_ws, size_t ws_size,
                              hipStream_t stream) {
    const int*      bits   = (const int*)d_in[0];
    const float*    tables = (const float*)d_in[1];
    float*          out    = (float*)d_out;
    unsigned*       packed = (unsigned*)d_ws;                       // 8 KB
    unsigned short* rowv   = (unsigned short*)((char*)d_ws + 8192); // 8 MB

    int nrows    = in_sizes[0] / 16;       // 4194304
    int nquarter = nrows * 4;              // 16777216

    pack_tables_kernel<<<65536 / 256, 256, 0, stream>>>(tables, packed);

    compress_kernel<<<nquarter / 256, 256, 0, stream>>>((const int4*)bits, rowv);

    // 4 quarters/thread -> 1024 quarters/block. Launched TWICE (idempotent):
    // e2e delta vs R6 = one expand dispatch's duration (attribution probe).
    expand_kernel<<<nquarter / 1024, 256, 0, stream>>>(rowv, packed,
                                                       (vfloat4*)out);
    expand_kernel<<<nquarter / 1024, 256, 0, stream>>>(rowv, packed,
                                                       (vfloat4*)out);
}

// Round 9
// 433.665 us; speedup vs baseline: 1.0933x; 1.0933x over previous
//
#include <hip/hip_runtime.h>
#include <hip/hip_bf16.h>

// BitLevelMapper: bits [B,16] int32 {0,1} (mem index j holds value bit 15-j),
// tables [16, 32768] float32 {0,1}. For bit i: addr = value of bits 0..i-1,
// flip = tables[i][addr], out bit i = bit i ^ flip. Output float32, reversed
// layout like input.
//
// R6: two unidirectional passes via 8 MB intermediate. R8 probe: expand =
// 45.3 us (write floor, 5.8 TB/s) -> compress+pack ~100 us (reads at only
// ~2.7 TB/s) is the remaining target.
// R9: deep-MLP persistent compress — 2048 blocks, 8 independent nt loads
// in flight per thread (8 KB/wave) before any processing.

#define PACK_WORDS 2048   // 65536 bits (65535 used), 8 KB

typedef float vfloat4 __attribute__((ext_vector_type(4)));
typedef int   vint4  __attribute__((ext_vector_type(4)));

__global__ __launch_bounds__(256) void
pack_tables_kernel(const float* __restrict__ tables, unsigned* __restrict__ packed) {
    int g = blockIdx.x * blockDim.x + threadIdx.x;   // global bit index
    bool val = false;
    if (g < 65535) {
        int i = 31 - __clz(g + 1);            // row: (2^i - 1) <= g < (2^{i+1} - 1)
        int a = g - ((1 << i) - 1);           // address within row
        val = tables[i * 32768 + a] != 0.0f;
    }
    unsigned long long m = __ballot(val);
    if ((threadIdx.x & 63) == 0) {            // one writer per wave, 2 words
        packed[(g >> 5)]     = (unsigned)m;
        packed[(g >> 5) + 1] = (unsigned)(m >> 32);
    }
}

// Pass A: bits (int32 {0,1}) -> packed 16-bit row values (8 MB).
// Persistent: 8 coalesced load streams per iteration, all issued before use.
// Lane with t&3==q holds quarter q of row t>>2; quad OR-butterfly assembles
// the row value; lane q==0 stores one ushort (16 consecutive/wave).
__global__ __launch_bounds__(256) void
compress_kernel(const vint4* __restrict__ bits4, unsigned short* __restrict__ rowv,
                int nquarter) {
    const int tid      = blockIdx.x * 256 + threadIdx.x;
    const int nthreads = gridDim.x * 256;           // multiple of 4
    const int q4       = (int)(threadIdx.x & 3) << 2;
    const int iters    = nquarter / (nthreads * 8); // exact for this problem

    for (int i = 0; i < iters; ++i) {
        const int t0 = tid + i * 8 * nthreads;
        vint4 b[8];
        #pragma unroll
        for (int s = 0; s < 8; ++s)                 // 8 loads in flight (8 KB/wave)
            b[s] = __builtin_nontemporal_load(&bits4[t0 + s * nthreads]);

        #pragma unroll
        for (int s = 0; s < 8; ++s) {
            unsigned nb = (unsigned)((b[s].x << 3) | (b[s].y << 2) |
                                     (b[s].z << 1) |  b[s].w);
            unsigned part = nb << (12 - q4);
            part |= (unsigned)__shfl_xor((int)part, 1, 64);
            part |= (unsigned)__shfl_xor((int)part, 2, 64);
            if (q4 == 0)
                rowv[(t0 + s * nthreads) >> 2] = (unsigned short)part;
        }
    }
}

// Pass B (R8-verified at write floor): packed row values + packed table ->
// float32 output. Thread handles 4 quarter-rows (one nt float4 store each).
__global__ __launch_bounds__(256) void
expand_kernel(const unsigned short* __restrict__ rowv,
              const unsigned* __restrict__ packed,
              vfloat4* __restrict__ out4) {
    __shared__ unsigned tab[PACK_WORDS];
    {   // stage 8 KB table (512 int4 / 256 threads = 2 each)
        const int4* p4 = (const int4*)packed;
        int4* t4 = (int4*)tab;
        t4[threadIdx.x]       = p4[threadIdx.x];
        t4[threadIdx.x + 256] = p4[threadIdx.x + 256];
    }
    __syncthreads();

    const size_t base = (size_t)blockIdx.x * 1024 + threadIdx.x;
    const int q4 = (int)(threadIdx.x & 3) << 2;      // 4*q, invariant across iters
    #pragma unroll
    for (int it = 0; it < 4; ++it) {
        size_t t = base + (size_t)it * 256;          // quarter index
        unsigned v = rowv[t >> 2];                   // 4 lanes share a row
        float o[4];
        #pragma unroll
        for (int j = 0; j < 4; ++j) {
            int i = 15 - q4 - j;                     // value bit for this slot
            unsigned mask = (1u << i) - 1u;
            unsigned bidx = mask + (v & mask);       // (2^i-1) + addr
            unsigned fl   = tab[bidx >> 5] >> (bidx & 31u);
            o[j] = (float)(((v >> i) ^ fl) & 1u);
        }
        vfloat4 f = {o[0], o[1], o[2], o[3]};
        __builtin_nontemporal_store(f, &out4[t]);
    }
}

extern "C" void kernel_launch(void* const* d_in, const int* in_sizes, int n_in,
                              void* d_out, int out_size, void* d_ws, size_t ws_size,
                              hipStream_t stream) {
    const int*      bits   = (const int*)d_in[0];
    const float*    tables = (const float*)d_in[1];
    float*          out    = (float*)d_out;
    unsigned*       packed = (unsigned*)d_ws;                       // 8 KB
    unsigned short* rowv   = (unsigned short*)((char*)d_ws + 8192); // 8 MB

    int nrows    = in_sizes[0] / 16;       // 4194304
    int nquarter = nrows * 4;              // 16777216

    pack_tables_kernel<<<65536 / 256, 256, 0, stream>>>(tables, packed);

    // 2048 blocks = 8/CU co-resident (no LDS), 524288 threads,
    // 32 quarters/thread = 4 iters x 8-deep load batches.
    compress_kernel<<<2048, 256, 0, stream>>>((const vint4*)bits, rowv, nquarter);

    // 4 quarters/thread -> 1024 quarters/block
    expand_kernel<<<nquarter / 1024, 256, 0, stream>>>(rowv, packed,
                                                       (vfloat4*)out);
}

// Round 10
// 432.311 us; speedup vs baseline: 1.0968x; 1.0031x over previous
//
#include <hip/hip_runtime.h>
#include <hip/hip_bf16.h>

// BitLevelMapper: bits [B,16] int32 {0,1} (mem index j holds value bit 15-j),
// tables [16, 32768] float32 {0,1}. For bit i: addr = value of bits 0..i-1,
// flip = tables[i][addr], out bit i = bit i ^ flip. Output float32, reversed
// layout like input.
//
// Established (R6/R8/R9): two unidirectional passes via 8 MB intermediate.
// Reads pin at ~2.8 TB/s (== m13's implied read ceiling ~3.15; invariant to
// MLP depth / persistence / nt), writes at ~5.8-6.6 TB/s. expand measured
// 45.3 us (write floor). R10: structural shave only — pack folded into the
// first 256 compress blocks (kills 1 dispatch + gap; compress doesn't read
// the packed table), expand persistent 4096 blocks (4x fewer LDS stagings).

#define PACK_WORDS 2048   // 65536 bits (65535 used), 8 KB

typedef float vfloat4 __attribute__((ext_vector_type(4)));

// Pass A: bits -> packed 16-bit row values (8 MB). One-shot, 1 quarter/thread.
// Blocks [0,256) additionally pack the flip table (1 iter each, ballot).
__global__ __launch_bounds__(256) void
compress_pack_kernel(const int4* __restrict__ bits4,
                     unsigned short* __restrict__ rowv,
                     const float* __restrict__ tables,
                     unsigned* __restrict__ packed) {
    if (blockIdx.x < 256) {                   // embedded table pack
        int g = blockIdx.x * 256 + threadIdx.x;   // global bit index
        bool val = false;
        if (g < 65535) {
            int i = 31 - __clz(g + 1);        // row: (2^i - 1) <= g < (2^{i+1} - 1)
            int a = g - ((1 << i) - 1);       // address within row
            val = tables[i * 32768 + a] != 0.0f;
        }
        unsigned long long m = __ballot(val);
        if ((threadIdx.x & 63) == 0) {        // one writer per wave, 2 words
            packed[(g >> 5)]     = (unsigned)m;
            packed[(g >> 5) + 1] = (unsigned)(m >> 32);
        }
    }

    // compress: lane t&3=q holds quarter q of row t>>2 (coalesced 16 B/lane)
    int t = blockIdx.x * 256 + threadIdx.x;
    int4 m4 = bits4[t];
    // nibble bit3 = first element in memory order = value bit 15-4q
    unsigned nb = (unsigned)((m4.x << 3) | (m4.y << 2) | (m4.z << 1) | m4.w);
    unsigned part = nb << (12 - ((t & 3) << 2));
    part |= (unsigned)__shfl_xor((int)part, 1, 64);
    part |= (unsigned)__shfl_xor((int)part, 2, 64);
    if ((t & 3) == 0)
        rowv[t >> 2] = (unsigned short)part;  // 16 consecutive ushorts / wave
}

// Pass B: packed row values + packed table -> float32 output (256 MB).
// Persistent 4096 blocks x 4 units; thread does one nt float4 store per iter.
__global__ __launch_bounds__(256) void
expand_kernel(const unsigned short* __restrict__ rowv,
              const unsigned* __restrict__ packed,
              vfloat4* __restrict__ out4) {
    __shared__ unsigned tab[PACK_WORDS];
    {   // stage 8 KB table (512 int4 / 256 threads = 2 each)
        const int4* p4 = (const int4*)packed;
        int4* t4 = (int4*)tab;
        t4[threadIdx.x]       = p4[threadIdx.x];
        t4[threadIdx.x + 256] = p4[threadIdx.x + 256];
    }
    __syncthreads();

    const int q4 = (int)(threadIdx.x & 3) << 2;      // 4*q, loop-invariant
    #pragma unroll
    for (int u = 0; u < 4; ++u) {
        const size_t base = ((size_t)blockIdx.x * 4 + u) * 1024 + threadIdx.x;
        #pragma unroll
        for (int it = 0; it < 4; ++it) {
            size_t t = base + (size_t)it * 256;      // quarter index
            unsigned v = rowv[t >> 2];               // 4 lanes share a row (bcast)
            float o[4];
            #pragma unroll
            for (int j = 0; j < 4; ++j) {
                int i = 15 - q4 - j;                 // value bit for this slot
                unsigned mask = (1u << i) - 1u;
                unsigned bidx = mask + (v & mask);   // (2^i-1) + addr
                unsigned fl   = tab[bidx >> 5] >> (bidx & 31u);
                o[j] = (float)(((v >> i) ^ fl) & 1u);
            }
            vfloat4 f = {o[0], o[1], o[2], o[3]};
            __builtin_nontemporal_store(f, &out4[t]);
        }
    }
}

extern "C" void kernel_launch(void* const* d_in, const int* in_sizes, int n_in,
                              void* d_out, int out_size, void* d_ws, size_t ws_size,
                              hipStream_t stream) {
    const int*      bits   = (const int*)d_in[0];
    const float*    tables = (const float*)d_in[1];
    float*          out    = (float*)d_out;
    unsigned*       packed = (unsigned*)d_ws;                       // 8 KB
    unsigned short* rowv   = (unsigned short*)((char*)d_ws + 8192); // 8 MB

    int nrows    = in_sizes[0] / 16;       // 4194304
    int nquarter = nrows * 4;              // 16777216

    // Pass A: 65536 blocks, 1 quarter/thread; first 256 blocks also pack the
    // table (expand is the only consumer of `packed`, so ordering is safe).
    compress_pack_kernel<<<nquarter / 256, 256, 0, stream>>>(
        (const int4*)bits, rowv, tables, packed);

    // Pass B: persistent 4096 blocks x 4 units x 4 float4/thread.
    expand_kernel<<<4096, 256, 0, stream>>>(rowv, packed, (vfloat4*)out);
}